// Round 8
// baseline (146.998 us; speedup 1.0000x reference)
//
#include <hip/hip_runtime.h>
#include <hip/hip_bf16.h>
#include <math.h>

static constexpr int T_TOK = 16384;   // 4*4096 tokens
static constexpr int E     = 256;     // experts
static constexpr int H     = 2048;    // hidden dim

typedef __attribute__((ext_vector_type(8))) short          bf16x8;
typedef __attribute__((ext_vector_type(8))) unsigned short u16x8;
typedef __attribute__((ext_vector_type(4))) float          f32x4;

// Exact 3-way bf16 split: x == h + m + l (24 mantissa bits, RN at each stage).
__device__ __forceinline__ void split3(float x, unsigned short& h,
                                       unsigned short& m, unsigned short& l) {
    __hip_bfloat16 bh = __float2bfloat16(x);
    float fh = __bfloat162float(bh);
    float r1 = x - fh;                      // exact
    __hip_bfloat16 bm = __float2bfloat16(r1);
    float fm = __bfloat162float(bm);
    float r2 = r1 - fm;                     // exact
    __hip_bfloat16 bl = __float2bfloat16(r2);
    h = *(unsigned short*)&bh; m = *(unsigned short*)&bm; l = *(unsigned short*)&bl;
}

// async 16B global -> LDS (width-16 variant; dest must be wave-uniform+lane*16)
__device__ __forceinline__ void gload_lds16(const unsigned short* g,
                                            unsigned short* l) {
    __builtin_amdgcn_global_load_lds(
        (const __attribute__((address_space(1))) unsigned int*)g,
        (__attribute__((address_space(3))) unsigned int*)l, 16, 0, 0);
}

// ---------------------------------------------------------------------------
// Kernel 0: split W [256][2048] fp32 into three bf16 planes (same layout).
// ---------------------------------------------------------------------------
__global__ __launch_bounds__(256) void prep_w(const float* __restrict__ W,
                                              unsigned short* __restrict__ Wh,
                                              unsigned short* __restrict__ Wm,
                                              unsigned short* __restrict__ Wl) {
    const int i = (blockIdx.x * 256 + threadIdx.x) * 4;
    float4 x = *(const float4*)(W + i);
    unsigned short h[4], m[4], l[4];
    split3(x.x, h[0], m[0], l[0]);
    split3(x.y, h[1], m[1], l[1]);
    split3(x.z, h[2], m[2], l[2]);
    split3(x.w, h[3], m[3], l[3]);
#pragma unroll
    for (int q = 0; q < 4; ++q) { Wh[i+q] = h[q]; Wm[i+q] = m[q]; Wl[i+q] = l[q]; }
}

// ---------------------------------------------------------------------------
// Kernel 1: partial logits via bf16x3 MFMA (6 passes: hh,hm,mh,mm,hl,lh).
// Block 128 tokens x 128 experts, 4 waves (2Mx2N), wave tile 64x64 = 4x4
// frags of mfma_f32_16x16x32_bf16. BK=32. Split-K over blockIdx.z.
// A: fp32 regs -> split3 -> ds_write (single-buffered, 24 KB).
// B: global_load_lds width-16, DOUBLE-buffered (48 KB) -- no VGPR roundtrip,
//    no ds_writes; t+1 loads issued after barrier #1 land during the A-write
//    phase (W planes are L2-resident). LDS dest = wave_base + lane*16.
// ---------------------------------------------------------------------------
__global__ __launch_bounds__(256, 2) void gemm_logits(
        const float* __restrict__ X,
        const unsigned short* __restrict__ Wh,
        const unsigned short* __restrict__ Wm,
        const unsigned short* __restrict__ Wl,
        float* __restrict__ Cp, int klen) {
    __shared__ __align__(16) unsigned short As[3][4][128][8];        // 24 KB
    __shared__ __align__(16) unsigned short Bsd[2][3][4][128][8];    // 48 KB

    const int tid  = threadIdx.x;
    const int lane = tid & 63;
    const int wid  = tid >> 6;            // 0..3
    const int wm   = wid >> 1, wn = wid & 1;
    const int bn   = blockIdx.x;          // 0..1  expert block (128)
    const int bm   = blockIdx.y;          // 0..127 token block (128)
    const int kz   = blockIdx.z;
    const int kbase = kz * klen;
    const int TB   = bm * 128;
    const int eb   = bn * 128;

    // A staging coords: thread owns row=tid>>1, k-half=(tid&1)*16
    const int srow  = tid >> 1;
    const int hh    = tid & 1;
    const int halfk = hh * 16;
    const int kc0   = hh * 2;

    // B staging coords (linear LDS): thread tid covers LDS offsets tid*16 and
    // (tid+256)*16 of each 8 KB plane tile -> (kc=tid>>7, row=tid&127) and
    // (kc+2, same row). Global source is per-lane reordered to match.
    const int brow = tid & 127;
    const int bkc  = tid >> 7;            // 0..1

    const float* Xp = X + (size_t)(TB + srow) * H + kbase + halfk;
    const unsigned short* WB[3] = {
        Wh + (size_t)(eb + brow) * H + kbase + bkc * 8,
        Wm + (size_t)(eb + brow) * H + kbase + bkc * 8,
        Wl + (size_t)(eb + brow) * H + kbase + bkc * 8 };
    // LDS linear targets for this thread within a plane tile
    const int ldsOff0 = tid * 16;         // u16 units: tid*16 elems = tid*32 B? no:
    // NB: offsets below are in ELEMENTS (u16). tid*16 elems == 32B*tid -> WRONG.
    // We want byte offset tid*16 -> element offset tid*8.
    const int eOff0 = tid * 8;            // elements (16 B)
    const int eOff1 = (tid + 256) * 8;

    const int frow = lane & 15;
    const int fkc  = lane >> 4;           // k-chunk 0..3

    float4 ax0, ax1, ax2, ax3;
    ax0 = *(const float4*)(Xp + 0);  ax1 = *(const float4*)(Xp + 4);
    ax2 = *(const float4*)(Xp + 8);  ax3 = *(const float4*)(Xp + 12);

    // prologue: B(kt=0) -> buffer 0
#pragma unroll
    for (int s = 0; s < 3; ++s) {
        unsigned short* pb = &Bsd[0][s][0][0][0];
        gload_lds16(WB[s],      pb + eOff0);
        gload_lds16(WB[s] + 16, pb + eOff1);   // kc+2 -> +16 elements in k
    }

    f32x4 acc[4][4];
#pragma unroll
    for (int i = 0; i < 4; ++i)
#pragma unroll
        for (int j = 0; j < 4; ++j) acc[i][j] = (f32x4){0.f, 0.f, 0.f, 0.f};

    const int NK = klen / 32;
    for (int kt = 0; kt < NK; ++kt) {
        const int cur = kt & 1;
        __syncthreads();   // (1) prior frag reads done; X prefetch drained

        // ---- issue B(kt+1) into the other buffer (async, no regs)
        if (kt + 1 < NK) {
#pragma unroll
            for (int s = 0; s < 3; ++s) {
                unsigned short* pb = &Bsd[cur ^ 1][s][0][0][0];
                const unsigned short* g = WB[s] + (kt + 1) * 32;
                gload_lds16(g,      pb + eOff0);
                gload_lds16(g + 16, pb + eOff1);
            }
        }

        // ---- write A planes (fp32 -> h,m,l bf16), contiguous 16B writes
        {
            float xv[16] = {ax0.x, ax0.y, ax0.z, ax0.w, ax1.x, ax1.y, ax1.z, ax1.w,
                            ax2.x, ax2.y, ax2.z, ax2.w, ax3.x, ax3.y, ax3.z, ax3.w};
            u16x8 vh0, vh1, vm0, vm1, vl0, vl1;
#pragma unroll
            for (int t = 0; t < 8; ++t) {
                unsigned short h, m, l;
                split3(xv[t], h, m, l);
                vh0[t] = h; vm0[t] = m; vl0[t] = l;
            }
#pragma unroll
            for (int t = 0; t < 8; ++t) {
                unsigned short h, m, l;
                split3(xv[8 + t], h, m, l);
                vh1[t] = h; vm1[t] = m; vl1[t] = l;
            }
            *(u16x8*)&As[0][kc0    ][srow][0] = vh0;
            *(u16x8*)&As[0][kc0 + 1][srow][0] = vh1;
            *(u16x8*)&As[1][kc0    ][srow][0] = vm0;
            *(u16x8*)&As[1][kc0 + 1][srow][0] = vm1;
            *(u16x8*)&As[2][kc0    ][srow][0] = vl0;
            *(u16x8*)&As[2][kc0 + 1][srow][0] = vl1;
        }

        __syncthreads();   // (2) A writes + B(kt) [+B(kt+1)] all visible

        // ---- prefetch X regs for kt+1 (hides under MFMAs)
        if (kt + 1 < NK) {
            const float* xn = Xp + (kt + 1) * 32;
            ax0 = *(const float4*)(xn + 0);  ax1 = *(const float4*)(xn + 4);
            ax2 = *(const float4*)(xn + 8);  ax3 = *(const float4*)(xn + 12);
        }

        // ---- phase 1: h + m planes -> 64 MFMAs
        bf16x8 afh[4], afx[4], bfh[4], bfx[4];
#pragma unroll
        for (int i = 0; i < 4; ++i) {
            afh[i] = *(const bf16x8*)&As[0][fkc][wm * 64 + i * 16 + frow][0];
            bfh[i] = *(const bf16x8*)&Bsd[cur][0][fkc][wn * 64 + i * 16 + frow][0];
            afx[i] = *(const bf16x8*)&As[1][fkc][wm * 64 + i * 16 + frow][0];
            bfx[i] = *(const bf16x8*)&Bsd[cur][1][fkc][wn * 64 + i * 16 + frow][0];
        }
#pragma unroll
        for (int i = 0; i < 4; ++i)
#pragma unroll
            for (int j = 0; j < 4; ++j)
                acc[i][j] = __builtin_amdgcn_mfma_f32_16x16x32_bf16(
                    afh[i], bfh[j], acc[i][j], 0, 0, 0);          // hh
#pragma unroll
        for (int i = 0; i < 4; ++i)
#pragma unroll
            for (int j = 0; j < 4; ++j)
                acc[i][j] = __builtin_amdgcn_mfma_f32_16x16x32_bf16(
                    afh[i], bfx[j], acc[i][j], 0, 0, 0);          // hm
#pragma unroll
        for (int i = 0; i < 4; ++i)
#pragma unroll
            for (int j = 0; j < 4; ++j)
                acc[i][j] = __builtin_amdgcn_mfma_f32_16x16x32_bf16(
                    afx[i], bfh[j], acc[i][j], 0, 0, 0);          // mh
#pragma unroll
        for (int i = 0; i < 4; ++i)
#pragma unroll
            for (int j = 0; j < 4; ++j)
                acc[i][j] = __builtin_amdgcn_mfma_f32_16x16x32_bf16(
                    afx[i], bfx[j], acc[i][j], 0, 0, 0);          // mm

        // ---- phase 2: l plane overwrites the m registers -> 32 MFMAs
#pragma unroll
        for (int i = 0; i < 4; ++i) {
            afx[i] = *(const bf16x8*)&As[2][fkc][wm * 64 + i * 16 + frow][0];
            bfx[i] = *(const bf16x8*)&Bsd[cur][2][fkc][wn * 64 + i * 16 + frow][0];
        }
#pragma unroll
        for (int i = 0; i < 4; ++i)
#pragma unroll
            for (int j = 0; j < 4; ++j)
                acc[i][j] = __builtin_amdgcn_mfma_f32_16x16x32_bf16(
                    afh[i], bfx[j], acc[i][j], 0, 0, 0);          // hl
#pragma unroll
        for (int i = 0; i < 4; ++i)
#pragma unroll
            for (int j = 0; j < 4; ++j)
                acc[i][j] = __builtin_amdgcn_mfma_f32_16x16x32_bf16(
                    afx[i], bfh[j], acc[i][j], 0, 0, 0);          // lh
    }

    // ---- epilogue: D layout col=lane&15, row=(lane>>4)*4+r
    float* Cz = Cp + (size_t)kz * T_TOK * E;
    const int rbase = (lane >> 4) * 4;
#pragma unroll
    for (int i = 0; i < 4; ++i)
#pragma unroll
        for (int j = 0; j < 4; ++j) {
            const int ecol = eb + wn * 64 + j * 16 + frow;
#pragma unroll
            for (int r = 0; r < 4; ++r) {
                const int tok = TB + wm * 64 + i * 16 + rbase + r;
                Cz[(size_t)tok * E + ecol] = acc[i][j][r];
            }
        }
}

// ---------------------------------------------------------------------------
// Kernel 2: fused split-K reduce + routing (proven). 16 lanes/token, 16
// experts/lane, all in registers; exact lax.top_k tie-breaks.
// ---------------------------------------------------------------------------
__global__ __launch_bounds__(256) void route_kernel(const float* __restrict__ P,
                                                    const float* __restrict__ bias,
                                                    float* __restrict__ out,
                                                    int nsplit) {
    const int sub = threadIdx.x & 15;
    const int tok = blockIdx.x * 16 + (threadIdx.x >> 4);
    const int ebase = sub * 16;

    double accd[16];
#pragma unroll
    for (int i = 0; i < 16; ++i) accd[i] = 0.0;
    for (int s = 0; s < nsplit; ++s) {
        const float* base = P + (size_t)s * T_TOK * E + (size_t)tok * E + ebase;
#pragma unroll
        for (int v = 0; v < 4; ++v) {
            float4 f = *(const float4*)(base + v * 4);
            accd[v * 4 + 0] += (double)f.x; accd[v * 4 + 1] += (double)f.y;
            accd[v * 4 + 2] += (double)f.z; accd[v * 4 + 3] += (double)f.w;
        }
    }

    float us[16], sc[16];
#pragma unroll
    for (int i = 0; i < 16; ++i) {
        float lg = (float)accd[i];
        double s = 1.0 / (1.0 + exp(-(double)lg));
        us[i] = (float)s;
        sc[i] = us[i] + bias[ebase + i];
    }

    float m1 = -1e30f, m2 = -1e30f;
#pragma unroll
    for (int i = 0; i < 16; ++i) {
        float s = sc[i];
        if (s > m1)      { m2 = m1; m1 = s; }
        else if (s > m2) { m2 = s; }
    }
    float pm1 = __shfl_xor(m1, 1, 16);
    float pm2 = __shfl_xor(m2, 1, 16);
    float gsum = (m1 >= pm1) ? (m1 + fmaxf(m2, pm1)) : (pm1 + fmaxf(pm2, m1));

    const int g = sub >> 1;
    int rank = 0;
#pragma unroll
    for (int h = 0; h < 8; ++h) {
        float gh = __shfl(gsum, h * 2, 16);
        if (h != g && (gh > gsum || (gh == gsum && h < g))) ++rank;
    }
    const bool sel = (rank < 4);

    unsigned used = 0;
    float myoi = 0.f, myow = 0.f;
    float wsum = 0.f;
#pragma unroll
    for (int p = 0; p < 8; ++p) {
        float bv = -1e30f; int bi = 0x7fff; float bu = 0.f;
#pragma unroll
        for (int i = 0; i < 16; ++i) {
            float v = ((used >> i) & 1u) ? -1e30f : (sel ? sc[i] : 0.0f);
            if (v > bv || (v == bv && (ebase + i) < bi)) {
                bv = v; bi = ebase + i; bu = us[i];
            }
        }
#pragma unroll
        for (int d = 1; d < 16; d <<= 1) {
            float ov = __shfl_xor(bv, d, 16);
            int   oi = __shfl_xor(bi, d, 16);
            float ou = __shfl_xor(bu, d, 16);
            if (ov > bv || (ov == bv && oi < bi)) { bv = ov; bi = oi; bu = ou; }
        }
        if ((bi >> 4) == sub) used |= 1u << (bi & 15);
        if (sub == p) { myoi = (float)bi; myow = bu; }
        wsum += bu;
    }

    const float scale = 2.5f / (wsum + 1e-20f);
    if (sub < 8) {
        out[(size_t)tok * 8 + sub] = myoi;
        out[(size_t)T_TOK * 8 + (size_t)tok * 8 + sub] = myow * scale;
    }
}

// ---------------------------------------------------------------------------
extern "C" void kernel_launch(void* const* d_in, const int* in_sizes, int n_in,
                              void* d_out, int out_size, void* d_ws, size_t ws_size,
                              hipStream_t stream) {
    const float* X = (const float*)d_in[0];   // [4,4096,2048] fp32
    const float* W = (const float*)d_in[1];   // [256,2048]   fp32
    const float* B = (const float*)d_in[2];   // [256]        fp32
    float* out     = (float*)d_out;

    const size_t WE     = (size_t)E * H;                       // 524288
    const size_t planeB = WE * sizeof(unsigned short);         // 1 MB
    const size_t chunkB = (size_t)T_TOK * E * sizeof(float);   // 16 MB

    unsigned short* Wh = (unsigned short*)d_ws;
    unsigned short* Wm = Wh + WE;
    unsigned short* Wl = Wm + WE;
    float* part = (float*)((char*)d_ws + 3 * planeB);

    int nsplit = 1;
    if (ws_size >= 3 * planeB + 4 * chunkB)      nsplit = 4;
    else if (ws_size >= 3 * planeB + 2 * chunkB) nsplit = 2;
    const int klen = H / nsplit;

    prep_w<<<WE / (256 * 4), 256, 0, stream>>>(W, Wh, Wm, Wl);

    dim3 gg(E / 128, T_TOK / 128, nsplit);    // (2, 128, 4) = 1024 blocks
    gemm_logits<<<gg, 256, 0, stream>>>(X, Wh, Wm, Wl, part, klen);

    route_kernel<<<T_TOK / 16, 256, 0, stream>>>(part, B, out, nsplit);
}

// Round 9
// 131.393 us; speedup vs baseline: 1.1188x; 1.1188x over previous
//
#include <hip/hip_runtime.h>
#include <hip/hip_bf16.h>
#include <math.h>

static constexpr int T_TOK = 16384;   // 4*4096 tokens
static constexpr int E     = 256;     // experts
static constexpr int H     = 2048;    // hidden dim

typedef __attribute__((ext_vector_type(8))) short          bf16x8;
typedef __attribute__((ext_vector_type(8))) unsigned short u16x8;
typedef __attribute__((ext_vector_type(4))) float          f32x4;

// Exact 3-way bf16 split: x == h + m + l (24 mantissa bits, RN at each stage).
__device__ __forceinline__ void split3(float x, unsigned short& h,
                                       unsigned short& m, unsigned short& l) {
    __hip_bfloat16 bh = __float2bfloat16(x);
    float fh = __bfloat162float(bh);
    float r1 = x - fh;                      // exact
    __hip_bfloat16 bm = __float2bfloat16(r1);
    float fm = __bfloat162float(bm);
    float r2 = r1 - fm;                     // exact
    __hip_bfloat16 bl = __float2bfloat16(r2);
    h = *(unsigned short*)&bh; m = *(unsigned short*)&bm; l = *(unsigned short*)&bl;
}

// async 16B global -> LDS (dest = wave-uniform base + lane*16)
__device__ __forceinline__ void gload_lds16(const unsigned short* g,
                                            unsigned short* l) {
    __builtin_amdgcn_global_load_lds(
        (const __attribute__((address_space(1))) unsigned int*)g,
        (__attribute__((address_space(3))) unsigned int*)l, 16, 0, 0);
}

// ---------------------------------------------------------------------------
// Kernel 0: split W [256][2048] fp32 into three bf16 planes (same layout).
// ---------------------------------------------------------------------------
__global__ __launch_bounds__(256) void prep_w(const float* __restrict__ W,
                                              unsigned short* __restrict__ Wh,
                                              unsigned short* __restrict__ Wm,
                                              unsigned short* __restrict__ Wl) {
    const int i = (blockIdx.x * 256 + threadIdx.x) * 4;
    float4 x = *(const float4*)(W + i);
    unsigned short h[4], m[4], l[4];
    split3(x.x, h[0], m[0], l[0]);
    split3(x.y, h[1], m[1], l[1]);
    split3(x.z, h[2], m[2], l[2]);
    split3(x.w, h[3], m[3], l[3]);
#pragma unroll
    for (int q = 0; q < 4; ++q) { Wh[i+q] = h[q]; Wm[i+q] = m[q]; Wl[i+q] = l[q]; }
}

// ---------------------------------------------------------------------------
// Kernel 1: partial logits via bf16x3 MFMA (6 passes: hh,hm,mh,mm,hl,lh).
// Block = 256 tokens x 128 experts, 512 threads (8 waves, 4M x 2N), wave
// tile 64x64 = 4x4 frags of mfma_f32_16x16x32_bf16. BK=32. Split-K over z.
// Minimum-2-phase dbuf schedule (guide T3 recipe): BOTH A and B double-
// buffered (144 KB LDS), ONE barrier per K-step; all staging issued at the
// TOP of the step so the barrier's vmcnt drain finds loads landed. X regs
// ping-pong (named sets, manual 2-step unroll) so split3 consumes data
// loaded a full iteration earlier.
// ---------------------------------------------------------------------------
__global__ __launch_bounds__(512, 2) void gemm_logits(
        const float* __restrict__ X,
        const unsigned short* __restrict__ Wh,
        const unsigned short* __restrict__ Wm,
        const unsigned short* __restrict__ Wl,
        float* __restrict__ Cp, int klen) {
    __shared__ __align__(16) unsigned short As[2][3][4][256][8];   // 96 KB
    __shared__ __align__(16) unsigned short Bs[2][3][4][128][8];   // 48 KB

    const int tid  = threadIdx.x;
    const int lane = tid & 63;
    const int wid  = tid >> 6;            // 0..7
    const int wm   = wid >> 1, wn = wid & 1;   // 4M x 2N
    const int kz   = blockIdx.z;
    const int kbase = kz * klen;
    const int TB   = blockIdx.y * 256;
    const int eb   = blockIdx.x * 128;

    // A staging: thread owns row=tid>>1 (0..255), k-half=(tid&1)*16
    const int srow  = tid >> 1;
    const int kc0   = (tid & 1) * 2;
    const float* Xp = X + (size_t)(TB + srow) * H + kbase + (tid & 1) * 16;

    // B staging: one 16B gload per plane; LDS linear elem off = tid*8
    const int brow = tid & 127;
    const int bkc  = tid >> 7;            // 0..3
    const unsigned short* WB0 = Wh + (size_t)(eb + brow) * H + kbase + bkc * 8;
    const unsigned short* WB1 = Wm + (size_t)(eb + brow) * H + kbase + bkc * 8;
    const unsigned short* WB2 = Wl + (size_t)(eb + brow) * H + kbase + bkc * 8;
    const int eOffB = tid * 8;

    const int frow = lane & 15;
    const int fkc  = lane >> 4;           // k-chunk 0..3

    f32x4 acc[4][4];
#pragma unroll
    for (int i = 0; i < 4; ++i)
#pragma unroll
        for (int j = 0; j < 4; ++j) acc[i][j] = (f32x4){0.f, 0.f, 0.f, 0.f};

    const int NK = klen / 32;             // 16/32/64 -> always even

    // ---- split3 16 fp32 -> write one A buffer
#define A_STAGE(BUF, q0, q1, q2, q3)                                           \
    {                                                                          \
        float xv[16] = {q0.x, q0.y, q0.z, q0.w, q1.x, q1.y, q1.z, q1.w,        \
                        q2.x, q2.y, q2.z, q2.w, q3.x, q3.y, q3.z, q3.w};       \
        u16x8 vh0, vh1, vm0, vm1, vl0, vl1;                                    \
        _Pragma("unroll")                                                      \
        for (int t = 0; t < 8; ++t) {                                          \
            unsigned short h, m, l;                                            \
            split3(xv[t], h, m, l);                                            \
            vh0[t] = h; vm0[t] = m; vl0[t] = l;                                \
        }                                                                      \
        _Pragma("unroll")                                                      \
        for (int t = 0; t < 8; ++t) {                                          \
            unsigned short h, m, l;                                            \
            split3(xv[8 + t], h, m, l);                                        \
            vh1[t] = h; vm1[t] = m; vl1[t] = l;                                \
        }                                                                      \
        *(u16x8*)&As[BUF][0][kc0    ][srow][0] = vh0;                          \
        *(u16x8*)&As[BUF][0][kc0 + 1][srow][0] = vh1;                          \
        *(u16x8*)&As[BUF][1][kc0    ][srow][0] = vm0;                          \
        *(u16x8*)&As[BUF][1][kc0 + 1][srow][0] = vm1;                          \
        *(u16x8*)&As[BUF][2][kc0    ][srow][0] = vl0;                          \
        *(u16x8*)&As[BUF][2][kc0 + 1][srow][0] = vl1;                          \
    }

    // ---- one K-step: stage (kt+1)->buf NXT, issue X(kt+2)->N*, MFMA on CUR
#define KSTEP(KT, CUR, NXT, C0, C1, C2, C3, N0, N1, N2, N3)                    \
    {                                                                          \
        if ((KT) + 1 < NK) {                                                   \
            const int ko = ((KT) + 1) * 32;                                    \
            gload_lds16(WB0 + ko, &Bs[NXT][0][0][0][0] + eOffB);               \
            gload_lds16(WB1 + ko, &Bs[NXT][1][0][0][0] + eOffB);               \
            gload_lds16(WB2 + ko, &Bs[NXT][2][0][0][0] + eOffB);               \
            A_STAGE(NXT, C0, C1, C2, C3);                                      \
            if ((KT) + 2 < NK) {                                               \
                const float* xn = Xp + ((KT) + 2) * 32;                        \
                N0 = *(const float4*)(xn + 0);  N1 = *(const float4*)(xn + 4); \
                N2 = *(const float4*)(xn + 8);  N3 = *(const float4*)(xn + 12);\
            }                                                                  \
        }                                                                      \
        bf16x8 afh[4], afx[4], bfh[4], bfx[4];                                 \
        _Pragma("unroll")                                                      \
        for (int i = 0; i < 4; ++i) {                                          \
            afh[i] = *(const bf16x8*)&As[CUR][0][fkc][wm * 64 + i * 16 + frow][0]; \
            bfh[i] = *(const bf16x8*)&Bs[CUR][0][fkc][wn * 64 + i * 16 + frow][0]; \
            afx[i] = *(const bf16x8*)&As[CUR][1][fkc][wm * 64 + i * 16 + frow][0]; \
            bfx[i] = *(const bf16x8*)&Bs[CUR][1][fkc][wn * 64 + i * 16 + frow][0]; \
        }                                                                      \
        __builtin_amdgcn_s_setprio(1);                                         \
        _Pragma("unroll")                                                      \
        for (int i = 0; i < 4; ++i)                                            \
            _Pragma("unroll")                                                  \
            for (int j = 0; j < 4; ++j)                                        \
                acc[i][j] = __builtin_amdgcn_mfma_f32_16x16x32_bf16(           \
                    afh[i], bfh[j], acc[i][j], 0, 0, 0);                       \
        _Pragma("unroll")                                                      \
        for (int i = 0; i < 4; ++i)                                            \
            _Pragma("unroll")                                                  \
            for (int j = 0; j < 4; ++j)                                        \
                acc[i][j] = __builtin_amdgcn_mfma_f32_16x16x32_bf16(           \
                    afh[i], bfx[j], acc[i][j], 0, 0, 0);                       \
        _Pragma("unroll")                                                      \
        for (int i = 0; i < 4; ++i)                                            \
            _Pragma("unroll")                                                  \
            for (int j = 0; j < 4; ++j)                                        \
                acc[i][j] = __builtin_amdgcn_mfma_f32_16x16x32_bf16(           \
                    afx[i], bfh[j], acc[i][j], 0, 0, 0);                       \
        _Pragma("unroll")                                                      \
        for (int i = 0; i < 4; ++i)                                            \
            _Pragma("unroll")                                                  \
            for (int j = 0; j < 4; ++j)                                        \
                acc[i][j] = __builtin_amdgcn_mfma_f32_16x16x32_bf16(           \
                    afx[i], bfx[j], acc[i][j], 0, 0, 0);                       \
        __builtin_amdgcn_s_setprio(0);                                         \
        _Pragma("unroll")                                                      \
        for (int i = 0; i < 4; ++i) {                                          \
            afx[i] = *(const bf16x8*)&As[CUR][2][fkc][wm * 64 + i * 16 + frow][0]; \
            bfx[i] = *(const bf16x8*)&Bs[CUR][2][fkc][wn * 64 + i * 16 + frow][0]; \
        }                                                                      \
        __builtin_amdgcn_s_setprio(1);                                         \
        _Pragma("unroll")                                                      \
        for (int i = 0; i < 4; ++i)                                            \
            _Pragma("unroll")                                                  \
            for (int j = 0; j < 4; ++j)                                        \
                acc[i][j] = __builtin_amdgcn_mfma_f32_16x16x32_bf16(           \
                    afh[i], bfx[j], acc[i][j], 0, 0, 0);                       \
        _Pragma("unroll")                                                      \
        for (int i = 0; i < 4; ++i)                                            \
            _Pragma("unroll")                                                  \
            for (int j = 0; j < 4; ++j)                                        \
                acc[i][j] = __builtin_amdgcn_mfma_f32_16x16x32_bf16(           \
                    afx[i], bfh[j], acc[i][j], 0, 0, 0);                       \
        __builtin_amdgcn_s_setprio(0);                                         \
        __syncthreads();                                                       \
    }

    // ---- prologue: A(0)+B(0) into buf 0; issue X(1) into pong regs
    float4 pa0, pa1, pa2, pa3, pb0, pb1, pb2, pb3;
    pa0 = *(const float4*)(Xp + 0);  pa1 = *(const float4*)(Xp + 4);
    pa2 = *(const float4*)(Xp + 8);  pa3 = *(const float4*)(Xp + 12);
    A_STAGE(0, pa0, pa1, pa2, pa3);
    gload_lds16(WB0, &Bs[0][0][0][0][0] + eOffB);
    gload_lds16(WB1, &Bs[0][1][0][0][0] + eOffB);
    gload_lds16(WB2, &Bs[0][2][0][0][0] + eOffB);
    {
        const float* xn = Xp + 32;
        pb0 = *(const float4*)(xn + 0);  pb1 = *(const float4*)(xn + 4);
        pb2 = *(const float4*)(xn + 8);  pb3 = *(const float4*)(xn + 12);
    }
    __syncthreads();

    for (int kt = 0; kt < NK; kt += 2) {
        KSTEP(kt,     0, 1, pb0, pb1, pb2, pb3, pa0, pa1, pa2, pa3);
        KSTEP(kt + 1, 1, 0, pa0, pa1, pa2, pa3, pb0, pb1, pb2, pb3);
    }
#undef KSTEP
#undef A_STAGE

    // ---- epilogue: D layout col=lane&15, row=(lane>>4)*4+r
    float* Cz = Cp + (size_t)kz * T_TOK * E;
    const int rbase = (lane >> 4) * 4;
#pragma unroll
    for (int i = 0; i < 4; ++i)
#pragma unroll
        for (int j = 0; j < 4; ++j) {
            const int ecol = eb + wn * 64 + j * 16 + frow;
#pragma unroll
            for (int r = 0; r < 4; ++r) {
                const int tok = TB + wm * 64 + i * 16 + rbase + r;
                Cz[(size_t)tok * E + ecol] = acc[i][j][r];
            }
        }
}

// ---------------------------------------------------------------------------
// Kernel 2: fused split-K reduce + routing (proven). 16 lanes/token, 16
// experts/lane, all in registers; exact lax.top_k tie-breaks.
// ---------------------------------------------------------------------------
__global__ __launch_bounds__(256) void route_kernel(const float* __restrict__ P,
                                                    const float* __restrict__ bias,
                                                    float* __restrict__ out,
                                                    int nsplit) {
    const int sub = threadIdx.x & 15;
    const int tok = blockIdx.x * 16 + (threadIdx.x >> 4);
    const int ebase = sub * 16;

    double accd[16];
#pragma unroll
    for (int i = 0; i < 16; ++i) accd[i] = 0.0;
    for (int s = 0; s < nsplit; ++s) {
        const float* base = P + (size_t)s * T_TOK * E + (size_t)tok * E + ebase;
#pragma unroll
        for (int v = 0; v < 4; ++v) {
            float4 f = *(const float4*)(base + v * 4);
            accd[v * 4 + 0] += (double)f.x; accd[v * 4 + 1] += (double)f.y;
            accd[v * 4 + 2] += (double)f.z; accd[v * 4 + 3] += (double)f.w;
        }
    }

    float us[16], sc[16];
#pragma unroll
    for (int i = 0; i < 16; ++i) {
        float lg = (float)accd[i];
        double s = 1.0 / (1.0 + exp(-(double)lg));
        us[i] = (float)s;
        sc[i] = us[i] + bias[ebase + i];
    }

    float m1 = -1e30f, m2 = -1e30f;
#pragma unroll
    for (int i = 0; i < 16; ++i) {
        float s = sc[i];
        if (s > m1)      { m2 = m1; m1 = s; }
        else if (s > m2) { m2 = s; }
    }
    float pm1 = __shfl_xor(m1, 1, 16);
    float pm2 = __shfl_xor(m2, 1, 16);
    float gsum = (m1 >= pm1) ? (m1 + fmaxf(m2, pm1)) : (pm1 + fmaxf(pm2, m1));

    const int g = sub >> 1;
    int rank = 0;
#pragma unroll
    for (int h = 0; h < 8; ++h) {
        float gh = __shfl(gsum, h * 2, 16);
        if (h != g && (gh > gsum || (gh == gsum && h < g))) ++rank;
    }
    const bool sel = (rank < 4);

    unsigned used = 0;
    float myoi = 0.f, myow = 0.f;
    float wsum = 0.f;
#pragma unroll
    for (int p = 0; p < 8; ++p) {
        float bv = -1e30f; int bi = 0x7fff; float bu = 0.f;
#pragma unroll
        for (int i = 0; i < 16; ++i) {
            float v = ((used >> i) & 1u) ? -1e30f : (sel ? sc[i] : 0.0f);
            if (v > bv || (v == bv && (ebase + i) < bi)) {
                bv = v; bi = ebase + i; bu = us[i];
            }
        }
#pragma unroll
        for (int d = 1; d < 16; d <<= 1) {
            float ov = __shfl_xor(bv, d, 16);
            int   oi = __shfl_xor(bi, d, 16);
            float ou = __shfl_xor(bu, d, 16);
            if (ov > bv || (ov == bv && oi < bi)) { bv = ov; bi = oi; bu = ou; }
        }
        if ((bi >> 4) == sub) used |= 1u << (bi & 15);
        if (sub == p) { myoi = (float)bi; myow = bu; }
        wsum += bu;
    }

    const float scale = 2.5f / (wsum + 1e-20f);
    if (sub < 8) {
        out[(size_t)tok * 8 + sub] = myoi;
        out[(size_t)T_TOK * 8 + (size_t)tok * 8 + sub] = myow * scale;
    }
}

// ---------------------------------------------------------------------------
extern "C" void kernel_launch(void* const* d_in, const int* in_sizes, int n_in,
                              void* d_out, int out_size, void* d_ws, size_t ws_size,
                              hipStream_t stream) {
    const float* X = (const float*)d_in[0];   // [4,4096,2048] fp32
    const float* W = (const float*)d_in[1];   // [256,2048]   fp32
    const float* B = (const float*)d_in[2];   // [256]        fp32
    float* out     = (float*)d_out;

    const size_t WE     = (size_t)E * H;                       // 524288
    const size_t planeB = WE * sizeof(unsigned short);         // 1 MB
    const size_t chunkB = (size_t)T_TOK * E * sizeof(float);   // 16 MB

    unsigned short* Wh = (unsigned short*)d_ws;
    unsigned short* Wm = Wh + WE;
    unsigned short* Wl = Wm + WE;
    float* part = (float*)((char*)d_ws + 3 * planeB);

    int nsplit = 1;
    if (ws_size >= 3 * planeB + 4 * chunkB)      nsplit = 4;
    else if (ws_size >= 3 * planeB + 2 * chunkB) nsplit = 2;
    const int klen = H / nsplit;

    prep_w<<<WE / (256 * 4), 256, 0, stream>>>(W, Wh, Wm, Wl);

    dim3 gg(E / 128, T_TOK / 256, nsplit);    // (2, 64, 4) = 512 blocks
    gemm_logits<<<gg, 512, 0, stream>>>(X, Wh, Wm, Wl, part, klen);

    route_kernel<<<T_TOK / 16, 256, 0, stream>>>(part, B, out, nsplit);
}

// Round 10
// 112.210 us; speedup vs baseline: 1.3100x; 1.1710x over previous
//
#include <hip/hip_runtime.h>
#include <hip/hip_bf16.h>
#include <math.h>

static constexpr int T_TOK = 16384;   // 4*4096 tokens
static constexpr int E     = 256;     // experts
static constexpr int H     = 2048;    // hidden dim

typedef __attribute__((ext_vector_type(8))) _Float16       f16x8;
typedef __attribute__((ext_vector_type(8))) unsigned short u16x8;
typedef __attribute__((ext_vector_type(4))) float          f32x4;

// 2-way f16 split of a PRE-SCALED value: xs == h + m + eps, |eps| <~ 2^-22|xs|.
// Scaling keeps h and m in f16 normal range (see kernel_launch comments).
__device__ __forceinline__ void split2(float xs, unsigned short& h,
                                       unsigned short& m) {
    _Float16 hh = (_Float16)xs;        // RN f32->f16
    float fh = (float)hh;
    float r  = xs - fh;                // exact in f32
    _Float16 mm = (_Float16)r;         // RN
    h = *(unsigned short*)&hh; m = *(unsigned short*)&mm;
}

// async 16B global -> LDS (dest = wave-uniform base + lane*16)
__device__ __forceinline__ void gload_lds16(const unsigned short* g,
                                            unsigned short* l) {
    __builtin_amdgcn_global_load_lds(
        (const __attribute__((address_space(1))) unsigned int*)g,
        (__attribute__((address_space(3))) unsigned int*)l, 16, 0, 0);
}

// ---------------------------------------------------------------------------
// Kernel 0: split W*256 [256][2048] fp32 into two f16 planes (same layout).
// ---------------------------------------------------------------------------
__global__ __launch_bounds__(256) void prep_w(const float* __restrict__ W,
                                              unsigned short* __restrict__ Wh,
                                              unsigned short* __restrict__ Wm) {
    const int i = (blockIdx.x * 256 + threadIdx.x) * 4;
    float4 x = *(const float4*)(W + i);
    unsigned short h[4], m[4];
    split2(x.x * 256.f, h[0], m[0]);
    split2(x.y * 256.f, h[1], m[1]);
    split2(x.z * 256.f, h[2], m[2]);
    split2(x.w * 256.f, h[3], m[3]);
#pragma unroll
    for (int q = 0; q < 4; ++q) { Wh[i+q] = h[q]; Wm[i+q] = m[q]; }
}

// ---------------------------------------------------------------------------
// Kernel 1: partial logits via f16x2 MFMA (4 passes: hh,hm,mh,mm).
// Block = 128 tokens x 128 experts, 256 threads (4 waves, 2Mx2N), wave tile
// 64x64 = 4x4 frags of mfma_f32_16x16x32_f16. BK=32. Split-K over z.
// 2-phase dbuf schedule (round-9 proven): both A and B double-buffered,
// ONE barrier per K-step, staging issued at the top of the step.
// LDS = 64 KB -> 2 blocks/CU (cross-block overlap during barrier drains).
// ---------------------------------------------------------------------------
__global__ __launch_bounds__(256, 2) void gemm_logits(
        const float* __restrict__ X,
        const unsigned short* __restrict__ Wh,
        const unsigned short* __restrict__ Wm,
        float* __restrict__ Cp, int klen) {
    __shared__ __align__(16) unsigned short As[2][2][4][128][8];   // 32 KB
    __shared__ __align__(16) unsigned short Bs[2][2][4][128][8];   // 32 KB

    const int tid  = threadIdx.x;
    const int lane = tid & 63;
    const int wid  = tid >> 6;            // 0..3
    const int wm   = wid >> 1, wn = wid & 1;   // 2M x 2N
    const int kz   = blockIdx.z;
    const int kbase = kz * klen;
    const int TB   = blockIdx.y * 128;
    const int eb   = blockIdx.x * 128;

    // A staging: thread owns row=tid>>1 (0..127), k-half=(tid&1)*16
    const int srow = tid >> 1;
    const int kc0  = (tid & 1) * 2;
    const float* Xp = X + (size_t)(TB + srow) * H + kbase + (tid & 1) * 16;

    // B staging: 2 gloads per plane; LDS linear slot tid and tid+256
    const int brow = tid & 127;
    const int bkc  = tid >> 7;            // 0..1
    const unsigned short* WB0 = Wh + (size_t)(eb + brow) * H + kbase + bkc * 8;
    const unsigned short* WB1 = Wm + (size_t)(eb + brow) * H + kbase + bkc * 8;
    const int eOffB0 = tid * 8;           // elements (16 B)
    const int eOffB1 = (tid + 256) * 8;   // covers kc+2, same row

    const int frow = lane & 15;
    const int fkc  = lane >> 4;           // k-chunk 0..3

    f32x4 acc[4][4];
#pragma unroll
    for (int i = 0; i < 4; ++i)
#pragma unroll
        for (int j = 0; j < 4; ++j) acc[i][j] = (f32x4){0.f, 0.f, 0.f, 0.f};

    const int NK = klen / 32;             // nsplit 4/2/1 -> 16/32/64, even

    // ---- scale by 64, split2, write one A buffer (2 planes x 2 chunks)
#define A_STAGE(BUF, q0, q1, q2, q3)                                           \
    {                                                                          \
        float xv[16] = {q0.x, q0.y, q0.z, q0.w, q1.x, q1.y, q1.z, q1.w,        \
                        q2.x, q2.y, q2.z, q2.w, q3.x, q3.y, q3.z, q3.w};       \
        u16x8 vh0, vh1, vm0, vm1;                                              \
        _Pragma("unroll")                                                      \
        for (int t = 0; t < 8; ++t) {                                          \
            unsigned short h, m;                                               \
            split2(xv[t] * 64.f, h, m);                                        \
            vh0[t] = h; vm0[t] = m;                                            \
        }                                                                      \
        _Pragma("unroll")                                                      \
        for (int t = 0; t < 8; ++t) {                                          \
            unsigned short h, m;                                               \
            split2(xv[8 + t] * 64.f, h, m);                                    \
            vh1[t] = h; vm1[t] = m;                                            \
        }                                                                      \
        *(u16x8*)&As[BUF][0][kc0    ][srow][0] = vh0;                          \
        *(u16x8*)&As[BUF][0][kc0 + 1][srow][0] = vh1;                          \
        *(u16x8*)&As[BUF][1][kc0    ][srow][0] = vm0;                          \
        *(u16x8*)&As[BUF][1][kc0 + 1][srow][0] = vm1;                          \
    }

    // ---- one K-step: stage (kt+1)->NXT, issue X(kt+2)->N*, MFMA on CUR
#define KSTEP(KT, CUR, NXT, C0, C1, C2, C3, N0, N1, N2, N3)                    \
    {                                                                          \
        if ((KT) + 1 < NK) {                                                   \
            const int ko = ((KT) + 1) * 32;                                    \
            gload_lds16(WB0 + ko,      &Bs[NXT][0][0][0][0] + eOffB0);         \
            gload_lds16(WB0 + ko + 16, &Bs[NXT][0][0][0][0] + eOffB1);         \
            gload_lds16(WB1 + ko,      &Bs[NXT][1][0][0][0] + eOffB0);         \
            gload_lds16(WB1 + ko + 16, &Bs[NXT][1][0][0][0] + eOffB1);         \
            A_STAGE(NXT, C0, C1, C2, C3);                                      \
            if ((KT) + 2 < NK) {                                               \
                const float* xn = Xp + ((KT) + 2) * 32;                        \
                N0 = *(const float4*)(xn + 0);  N1 = *(const float4*)(xn + 4); \
                N2 = *(const float4*)(xn + 8);  N3 = *(const float4*)(xn + 12);\
            }                                                                  \
        }                                                                      \
        f16x8 afh[4], afm[4], bfh[4], bfm[4];                                  \
        _Pragma("unroll")                                                      \
        for (int i = 0; i < 4; ++i) {                                          \
            afh[i] = *(const f16x8*)&As[CUR][0][fkc][wm * 64 + i * 16 + frow][0]; \
            bfh[i] = *(const f16x8*)&Bs[CUR][0][fkc][wn * 64 + i * 16 + frow][0]; \
            afm[i] = *(const f16x8*)&As[CUR][1][fkc][wm * 64 + i * 16 + frow][0]; \
            bfm[i] = *(const f16x8*)&Bs[CUR][1][fkc][wn * 64 + i * 16 + frow][0]; \
        }                                                                      \
        __builtin_amdgcn_s_setprio(1);                                         \
        _Pragma("unroll")                                                      \
        for (int i = 0; i < 4; ++i)                                            \
            _Pragma("unroll")                                                  \
            for (int j = 0; j < 4; ++j)                                        \
                acc[i][j] = __builtin_amdgcn_mfma_f32_16x16x32_f16(            \
                    afh[i], bfh[j], acc[i][j], 0, 0, 0);                       \
        _Pragma("unroll")                                                      \
        for (int i = 0; i < 4; ++i)                                            \
            _Pragma("unroll")                                                  \
            for (int j = 0; j < 4; ++j)                                        \
                acc[i][j] = __builtin_amdgcn_mfma_f32_16x16x32_f16(            \
                    afh[i], bfm[j], acc[i][j], 0, 0, 0);                       \
        _Pragma("unroll")                                                      \
        for (int i = 0; i < 4; ++i)                                            \
            _Pragma("unroll")                                                  \
            for (int j = 0; j < 4; ++j)                                        \
                acc[i][j] = __builtin_amdgcn_mfma_f32_16x16x32_f16(            \
                    afm[i], bfh[j], acc[i][j], 0, 0, 0);                       \
        _Pragma("unroll")                                                      \
        for (int i = 0; i < 4; ++i)                                            \
            _Pragma("unroll")                                                  \
            for (int j = 0; j < 4; ++j)                                        \
                acc[i][j] = __builtin_amdgcn_mfma_f32_16x16x32_f16(            \
                    afm[i], bfm[j], acc[i][j], 0, 0, 0);                       \
        __builtin_amdgcn_s_setprio(0);                                         \
        __syncthreads();                                                       \
    }

    // ---- prologue: A(0)+B(0) into buf 0; X(1) into pong regs
    float4 pa0, pa1, pa2, pa3, pb0, pb1, pb2, pb3;
    pa0 = *(const float4*)(Xp + 0);  pa1 = *(const float4*)(Xp + 4);
    pa2 = *(const float4*)(Xp + 8);  pa3 = *(const float4*)(Xp + 12);
    A_STAGE(0, pa0, pa1, pa2, pa3);
    gload_lds16(WB0,      &Bs[0][0][0][0][0] + eOffB0);
    gload_lds16(WB0 + 16, &Bs[0][0][0][0][0] + eOffB1);
    gload_lds16(WB1,      &Bs[0][1][0][0][0] + eOffB0);
    gload_lds16(WB1 + 16, &Bs[0][1][0][0][0] + eOffB1);
    {
        const float* xn = Xp + 32;
        pb0 = *(const float4*)(xn + 0);  pb1 = *(const float4*)(xn + 4);
        pb2 = *(const float4*)(xn + 8);  pb3 = *(const float4*)(xn + 12);
    }
    __syncthreads();

    for (int kt = 0; kt < NK; kt += 2) {
        KSTEP(kt,     0, 1, pb0, pb1, pb2, pb3, pa0, pa1, pa2, pa3);
        KSTEP(kt + 1, 1, 0, pa0, pa1, pa2, pa3, pb0, pb1, pb2, pb3);
    }
#undef KSTEP
#undef A_STAGE

    // ---- epilogue: D layout col=lane&15, row=(lane>>4)*4+r
    float* Cz = Cp + (size_t)kz * T_TOK * E;
    const int rbase = (lane >> 4) * 4;
#pragma unroll
    for (int i = 0; i < 4; ++i)
#pragma unroll
        for (int j = 0; j < 4; ++j) {
            const int ecol = eb + wn * 64 + j * 16 + frow;
#pragma unroll
            for (int r = 0; r < 4; ++r) {
                const int tok = TB + wm * 64 + i * 16 + rbase + r;
                Cz[(size_t)tok * E + ecol] = acc[i][j][r];
            }
        }
}

// ---------------------------------------------------------------------------
// Kernel 2: fused split-K reduce + routing (proven). 16 lanes/token, 16
// experts/lane, all in registers; exact lax.top_k tie-breaks. Logits are
// scaled by 2^14 (X*64, W*256) -> multiply by 2^-14 (exact) before sigmoid.
// ---------------------------------------------------------------------------
__global__ __launch_bounds__(256) void route_kernel(const float* __restrict__ P,
                                                    const float* __restrict__ bias,
                                                    float* __restrict__ out,
                                                    int nsplit) {
    const int sub = threadIdx.x & 15;
    const int tok = blockIdx.x * 16 + (threadIdx.x >> 4);
    const int ebase = sub * 16;

    double accd[16];
#pragma unroll
    for (int i = 0; i < 16; ++i) accd[i] = 0.0;
    for (int s = 0; s < nsplit; ++s) {
        const float* base = P + (size_t)s * T_TOK * E + (size_t)tok * E + ebase;
#pragma unroll
        for (int v = 0; v < 4; ++v) {
            float4 f = *(const float4*)(base + v * 4);
            accd[v * 4 + 0] += (double)f.x; accd[v * 4 + 1] += (double)f.y;
            accd[v * 4 + 2] += (double)f.z; accd[v * 4 + 3] += (double)f.w;
        }
    }

    float us[16], sc[16];
#pragma unroll
    for (int i = 0; i < 16; ++i) {
        float lg = (float)accd[i] * (1.f / 16384.f);   // exact pow2 unscale
        double s = 1.0 / (1.0 + exp(-(double)lg));
        us[i] = (float)s;
        sc[i] = us[i] + bias[ebase + i];
    }

    float m1 = -1e30f, m2 = -1e30f;
#pragma unroll
    for (int i = 0; i < 16; ++i) {
        float s = sc[i];
        if (s > m1)      { m2 = m1; m1 = s; }
        else if (s > m2) { m2 = s; }
    }
    float pm1 = __shfl_xor(m1, 1, 16);
    float pm2 = __shfl_xor(m2, 1, 16);
    float gsum = (m1 >= pm1) ? (m1 + fmaxf(m2, pm1)) : (pm1 + fmaxf(pm2, m1));

    const int g = sub >> 1;
    int rank = 0;
#pragma unroll
    for (int h = 0; h < 8; ++h) {
        float gh = __shfl(gsum, h * 2, 16);
        if (h != g && (gh > gsum || (gh == gsum && h < g))) ++rank;
    }
    const bool sel = (rank < 4);

    unsigned used = 0;
    float myoi = 0.f, myow = 0.f;
    float wsum = 0.f;
#pragma unroll
    for (int p = 0; p < 8; ++p) {
        float bv = -1e30f; int bi = 0x7fff; float bu = 0.f;
#pragma unroll
        for (int i = 0; i < 16; ++i) {
            float v = ((used >> i) & 1u) ? -1e30f : (sel ? sc[i] : 0.0f);
            if (v > bv || (v == bv && (ebase + i) < bi)) {
                bv = v; bi = ebase + i; bu = us[i];
            }
        }
#pragma unroll
        for (int d = 1; d < 16; d <<= 1) {
            float ov = __shfl_xor(bv, d, 16);
            int   oi = __shfl_xor(bi, d, 16);
            float ou = __shfl_xor(bu, d, 16);
            if (ov > bv || (ov == bv && oi < bi)) { bv = ov; bi = oi; bu = ou; }
        }
        if ((bi >> 4) == sub) used |= 1u << (bi & 15);
        if (sub == p) { myoi = (float)bi; myow = bu; }
        wsum += bu;
    }

    const float scale = 2.5f / (wsum + 1e-20f);
    if (sub < 8) {
        out[(size_t)tok * 8 + sub] = myoi;
        out[(size_t)T_TOK * 8 + (size_t)tok * 8 + sub] = myow * scale;
    }
}

// ---------------------------------------------------------------------------
extern "C" void kernel_launch(void* const* d_in, const int* in_sizes, int n_in,
                              void* d_out, int out_size, void* d_ws, size_t ws_size,
                              hipStream_t stream) {
    const float* X = (const float*)d_in[0];   // [4,4096,2048] fp32
    const float* W = (const float*)d_in[1];   // [256,2048]   fp32
    const float* B = (const float*)d_in[2];   // [256]        fp32
    float* out     = (float*)d_out;

    const size_t WE     = (size_t)E * H;                       // 524288
    const size_t planeB = WE * sizeof(unsigned short);         // 1 MB
    const size_t chunkB = (size_t)T_TOK * E * sizeof(float);   // 16 MB

    unsigned short* Wh = (unsigned short*)d_ws;
    unsigned short* Wm = Wh + WE;
    float* part = (float*)((char*)d_ws + 2 * planeB);

    int nsplit = 1;
    if (ws_size >= 2 * planeB + 4 * chunkB)      nsplit = 4;
    else if (ws_size >= 2 * planeB + 2 * chunkB) nsplit = 2;
    const int klen = H / nsplit;

    prep_w<<<WE / (256 * 4), 256, 0, stream>>>(W, Wh, Wm);

    dim3 gg(E / 128, T_TOK / 128, nsplit);    // (2, 128, 4) = 1024 blocks
    gemm_logits<<<gg, 256, 0, stream>>>(X, Wh, Wm, part, klen);

    route_kernel<<<T_TOK / 16, 256, 0, stream>>>(part, B, out, nsplit);
}